// Round 2
// baseline (453.217 us; speedup 1.0000x reference)
//
#include <hip/hip_runtime.h>

// ChainGNN: B=64, ENC_IN=64, ENC_HID=256, N=2048, GH=128
// Exploits: (1) A_hat tridiagonal (chain) -> neighbor mix, not dense matmul
//           (2) layer-2 collapse: y = out1@Wout + A*(LN(out1)@(Wg2@Wout)) + bout
//           (3) f16 MFMA for encoder GEMM (268MB W2 read is the HBM floor) and layer-1 GEMM
// R4: k_enc 256-col blocks -> 1KB contiguous per W2 row per DMA instr.
// R5: k_gcn reduction overhaul (LN2 algebraic collapse, half-wave fused reductions).
// R6: k_enc counted-vmcnt pipeline: raw s_barrier + s_waitcnt vmcnt(8) keeps 2 tiles
//     (64KB/block) continuously in flight across barriers (old __syncthreads drained
//     vmcnt(0) -> 32KB bursts with gaps). A-fragments double-buffered in registers,
//     issued in fixed vmcnt-queue order (af before next stage) so one counted wait
//     covers tile+af. k_gcn/k_prep untouched for attribution.

#define B_    64
#define EIN   64
#define EHID  256
#define NN    2048
#define GH    128
#define NG    (NN*GH)          // 262144
#define LN_EPS 1e-5f
#define C3    28               // nodes per k_gcn block (ext rows = 32 = 2 MFMA m-groups)

typedef _Float16 f16;
typedef _Float16 f16x8 __attribute__((ext_vector_type(8)));
typedef _Float16 f16x4 __attribute__((ext_vector_type(4)));
typedef _Float16 f16x2 __attribute__((ext_vector_type(2)));
typedef float    f32x4 __attribute__((ext_vector_type(4)));
typedef unsigned int u32;

#define AS1 __attribute__((address_space(1)))
#define AS3 __attribute__((address_space(3)))

__device__ __forceinline__ float wred64(float v) {
#pragma unroll
    for (int off = 32; off > 0; off >>= 1) v += __shfl_xor(v, off, 64);
    return v;
}

// ---- K1: h1=relu(x@W1+b1) f16 | Wg1^T f16 | u2=g2*(Wg2@Wout), S1/S0 scalars |
//          clo/chi off-diagonals ----
__global__ __launch_bounds__(256) void k_prep(
    const float* __restrict__ x,  const float* __restrict__ W1, const float* __restrict__ b1,
    const float* __restrict__ Wg1,const float* __restrict__ Wg2,const float* __restrict__ Wout,
    const float* __restrict__ A_hat,
    const float* __restrict__ ln_g2, const float* __restrict__ ln_b2,
    f16* __restrict__ h1h, f16* __restrict__ wg1T,
    float* __restrict__ u2, float* __restrict__ sc,
    float* __restrict__ clo, float* __restrict__ chi)
{
    int bid = blockIdx.x, tid = threadIdx.x;
    if (bid < 64) {
        int b = bid, j = tid;
        float acc = b1[j];
#pragma unroll 8
        for (int k = 0; k < EIN; ++k) acc = fmaf(x[b*EIN + k], W1[k*EHID + j], acc);
        h1h[b*EHID + j] = (f16)fmaxf(acc, 0.f);
    } else if (bid == 64) {
        __shared__ float tu[GH], tb[GH];
        if (tid < GH) {
            float s = 0.f;                       // v2[c] = (Wg2 @ Wout)[c]
            for (int j = 0; j < GH; ++j) s = fmaf(Wg2[tid*GH + j], Wout[j], s);
            float uu = ln_g2[tid] * s;           // u = g2 .* v2
            u2[tid] = uu;
            tu[tid] = uu;
            tb[tid] = ln_b2[tid] * s;            // b2 .* v2
        }
        __syncthreads();
        if (tid < 64) {
            float a = tu[tid] + tu[tid + 64];
            float b = tb[tid] + tb[tid + 64];
            a = wred64(a); b = wred64(b);
            if (tid == 0) { sc[0] = a; sc[1] = b; }   // S1, S0
        }
    } else if (bid == 65) {
        for (int i = tid; i < GH*GH; i += 256) {
            int n = i >> 7, k = i & 127;          // wg1T[n][k] = Wg1[k][n]
            wg1T[i] = (f16)Wg1[k*GH + n];
        }
    } else {
        int n = (bid - 66) * 256 + tid;           // bids 66..73 cover n = 0..2047
        clo[n] = (n >= 1)    ? A_hat[(size_t)n*NN + (n-1)] : 0.f;
        chi[n] = (n <= NN-2) ? A_hat[(size_t)n*NN + (n+1)] : 0.f;
    }
}

// ---- K2: out0 = h1 @ W2 + b2  (M=64,K=256,N=262144), f16 out ----
// 256 cols/block. W2 staged 32x256 fp32 double-buffered via global_load_lds dwordx4.
// R6 pipeline: per K-step: [s_waitcnt vmcnt(8); s_barrier; issue af(kk+1);
// compute(kk); s_barrier; stage(kk+2)]. vmcnt queue per wave (oldest->newest):
// stage(kk)[8], af(kk)[4], stage(kk+1)[8] -> vmcnt(8) retires exactly tile kk + af(kk).
__global__ __launch_bounds__(256) void k_enc(
    const float* __restrict__ W2, const float* __restrict__ b2,
    const f16* __restrict__ h1h, f16* __restrict__ out0)
{
    __shared__ float w2s[2][16*516];      // 2 x 33024 B

    int tid = threadIdx.x;
    int L = tid & 63, wv = tid >> 6, hi = L >> 4, lo = L & 15;
    int c0 = blockIdx.x * 256;

    auto stage = [&](int kk, int nb) {
#pragma unroll
        for (int s = 0; s < 8; ++s) {
            int r = wv*8 + s;
            const float* gp = W2 + (size_t)(kk*32 + r) * NG + c0 + L*4;
            float* ldst = &w2s[nb][(r >> 1)*516 + (r & 1)*256];
            __builtin_amdgcn_global_load_lds((const AS1 void*)gp, (AS3 void*)ldst, 16, 0, 0);
        }
    };

    f16x8 afq[2][4];                      // A-fragment double buffer (regs)
    auto load_af = [&](int kk, int pb) {
#pragma unroll
        for (int bg = 0; bg < 4; ++bg)
            afq[pb][bg] = *(const f16x8*)(h1h + ((bg*16 + lo) << 8) + kk*32 + hi*8);
    };

    // prologue: queue order = af(0)[4], stage(0)[8], stage(1)[8]
    load_af(0, 0);
    asm volatile("" ::: "memory");        // pin af(0) issue before stage(0)
    stage(0, 0);
    stage(1, 1);

    f32x4 acc[4][4];
#pragma unroll
    for (int bg = 0; bg < 4; ++bg)
#pragma unroll
        for (int t = 0; t < 4; ++t) acc[bg][t] = f32x4{0.f, 0.f, 0.f, 0.f};

#pragma unroll
    for (int kk = 0; kk < 8; ++kk) {
        // retire tile kk (my 8 stage loads) + af(kk); leave stage(kk+1) in flight
        if (kk < 7) asm volatile("s_waitcnt vmcnt(8)" ::: "memory");
        else        asm volatile("s_waitcnt vmcnt(0)" ::: "memory");
        __builtin_amdgcn_s_barrier();     // all waves' tile-kk rows resident
        asm volatile("" ::: "memory");    // no ds_read hoisted above the barrier

        if (kk < 7) load_af(kk + 1, (kk + 1) & 1);   // queue pos: before stage(kk+2)

        const float* wb = w2s[kk & 1];
        f16x8 bf[4];
#pragma unroll
        for (int t = 0; t < 4; ++t)
#pragma unroll
            for (int j = 0; j < 8; ++j) {
                int row = hi*8 + j;
                bf[t][j] = (f16)wb[(row >> 1)*516 + (row & 1)*256 + wv*64 + t*16 + lo];
            }

#pragma unroll
        for (int bg = 0; bg < 4; ++bg)
#pragma unroll
            for (int t = 0; t < 4; ++t)
                acc[bg][t] = __builtin_amdgcn_mfma_f32_16x16x32_f16(afq[kk & 1][bg], bf[t], acc[bg][t], 0, 0, 0);

        asm volatile("" ::: "memory");    // all buf[kk&1] reads retired (fed MFMAs)
        __builtin_amdgcn_s_barrier();     // all waves done reading buf[kk&1]
        asm volatile("" ::: "memory");    // stage not hoisted above barrier
        if (kk < 6) stage(kk + 2, kk & 1);
    }

    float bv[4];
#pragma unroll
    for (int t = 0; t < 4; ++t) bv[t] = b2[c0 + wv*64 + t*16 + lo];
#pragma unroll
    for (int bg = 0; bg < 4; ++bg)
#pragma unroll
        for (int t = 0; t < 4; ++t)
#pragma unroll
            for (int r = 0; r < 4; ++r) {
                int brow = bg*16 + hi*4 + r;      // C/D: row=(lane>>4)*4+reg, col=lane&15
                out0[(size_t)brow * NG + c0 + wv*64 + t*16 + lo] = (f16)(acc[bg][t][r] + bv[t]);
            }
}

// ---- K3 (fused GCN1+GCN2): per (b, 28-node chunk) ->
//   Wx0 = LN1(out0)@Wg1 (ext 32 rows), out1 = out0 + mix(Wx0) (rows 1..30, in LDS),
//   per row: [s,q,d,yp] fused reduction -> ss = inv*(d - mu*S1) + S0, yr = yp,
//   y = yr + bout + mix(ss).
__global__ __launch_bounds__(256) void k_gcn(
    const float* __restrict__ clo, const float* __restrict__ chi,
    const float* __restrict__ ln_g1, const float* __restrict__ ln_b1,
    const float* __restrict__ Wout, const float* __restrict__ bout,
    const float* __restrict__ u2, const float* __restrict__ sc,
    const f16* __restrict__ wg1T,
    const f16* __restrict__ out0, float* __restrict__ y)
{
    __shared__ f16 out0_s[32][136];      // ext rows: nodes n0-2 .. n0+29 (becomes out1 in place)
    __shared__ f16 h0s[32][136];
    __shared__ f16 wx0_s[32][136];
    __shared__ alignas(16) float g1s[GH], b1s[GH], u2s[GH], wos[GH];
    __shared__ float cls[32], chs[32];
    __shared__ float ss[32], yrs[32], scs[2];

    int tid = threadIdx.x;
    int n0 = blockIdx.x * C3;
    int b  = blockIdx.y;

    for (int i = tid; i < 32*16; i += 256) {
        int r = i >> 4, gv = i & 15;
        int n = n0 - 2 + r;
        f16x8 v = {0,0,0,0,0,0,0,0};
        if (n >= 0 && n < NN) v = *(const f16x8*)(out0 + ((size_t)b*NN + n)*GH + gv*8);
        *(f16x8*)&out0_s[r][gv*8] = v;
    }
    if (tid < GH) {
        g1s[tid] = ln_g1[tid]; b1s[tid] = ln_b1[tid];
        u2s[tid] = u2[tid];    wos[tid] = Wout[tid];
    } else if (tid < GH + 32) {
        int r = tid - GH, n = n0 - 2 + r;
        bool ok = (n >= 0 && n < NN);
        cls[r] = ok ? clo[n] : 0.f;
        chs[r] = ok ? chi[n] : 0.f;
    } else if (tid == GH + 32) {
        scs[0] = sc[0]; scs[1] = sc[1];
    }
    __syncthreads();

    int L = tid & 63, wv = tid >> 6, hi = L >> 4, lo = L & 15;
    int half = L >> 5, l32 = L & 31;

    // LN1 over all 32 ext rows: one row per 32-lane half, 4 channels/lane
    {
        f32x4 g1v = *(const f32x4*)&g1s[l32*4];
        f32x4 b1v = *(const f32x4*)&b1s[l32*4];
#pragma unroll
        for (int rp = wv*2 + half; rp < 32; rp += 8) {
            f16x4 xv = *(const f16x4*)&out0_s[rp][l32*4];
            float x0 = (float)xv[0], x1 = (float)xv[1], x2 = (float)xv[2], x3 = (float)xv[3];
            float s = (x0 + x1) + (x2 + x3);
            float q = (x0*x0 + x1*x1) + (x2*x2 + x3*x3);
#pragma unroll
            for (int off = 16; off > 0; off >>= 1) {
                s += __shfl_xor(s, off, 64);
                q += __shfl_xor(q, off, 64);
            }
            float mu  = s * (1.f/128.f);
            float inv = rsqrtf(q*(1.f/128.f) - mu*mu + LN_EPS);
            f16x4 h;
            h[0] = (f16)((x0 - mu)*inv*g1v[0] + b1v[0]);
            h[1] = (f16)((x1 - mu)*inv*g1v[1] + b1v[1]);
            h[2] = (f16)((x2 - mu)*inv*g1v[2] + b1v[2]);
            h[3] = (f16)((x3 - mu)*inv*g1v[3] + b1v[3]);
            *(f16x4*)&h0s[rp][l32*4] = h;
        }
    }
    __syncthreads();

    // Wx0 = h0 @ Wg1 : M=32, N=128, K=128. B fragments straight from L2-hot wg1T.
    f32x4 acc[2][2];
#pragma unroll
    for (int mg = 0; mg < 2; ++mg)
#pragma unroll
        for (int nt = 0; nt < 2; ++nt) acc[mg][nt] = f32x4{0.f, 0.f, 0.f, 0.f};

#pragma unroll
    for (int kk = 0; kk < 4; ++kk) {
        f16x8 af[2], bfr[2];
#pragma unroll
        for (int mg = 0; mg < 2; ++mg)
            af[mg] = *(const f16x8*)&h0s[mg*16 + lo][kk*32 + hi*8];
#pragma unroll
        for (int nt = 0; nt < 2; ++nt) {
            int n = wv*32 + nt*16 + lo;
            bfr[nt] = *(const f16x8*)(wg1T + n*GH + kk*32 + hi*8);
        }
#pragma unroll
        for (int mg = 0; mg < 2; ++mg)
#pragma unroll
            for (int nt = 0; nt < 2; ++nt)
                acc[mg][nt] = __builtin_amdgcn_mfma_f32_16x16x32_f16(af[mg], bfr[nt], acc[mg][nt], 0, 0, 0);
    }
#pragma unroll
    for (int mg = 0; mg < 2; ++mg)
#pragma unroll
        for (int nt = 0; nt < 2; ++nt)
#pragma unroll
            for (int r = 0; r < 4; ++r)
                wx0_s[mg*16 + hi*4 + r][wv*32 + nt*16 + lo] = (f16)acc[mg][nt][r];
    __syncthreads();

    // out1 rows 1..30 in place: out1[r] = out0[r] + cls[r]*Wx0[r-1] + chs[r]*Wx0[r+1]
    for (int i = tid; i < 30*64; i += 256) {
        int r = 1 + (i >> 6), gp = (i & 63) * 2;
        float c_lo = cls[r], c_hi = chs[r];
        f16x2 o = *(const f16x2*)&out0_s[r][gp];
        f16x2 a = *(const f16x2*)&wx0_s[r-1][gp];
        f16x2 c = *(const f16x2*)&wx0_s[r+1][gp];
        f16x2 res;
        res[0] = (f16)((float)o[0] + c_lo*(float)a[0] + c_hi*(float)c[0]);
        res[1] = (f16)((float)o[1] + c_lo*(float)a[1] + c_hi*(float)c[1]);
        *(f16x2*)&out0_s[r][gp] = res;
    }
    __syncthreads();

    // LN2 collapsed: per row need only s=Σx, q=Σx², d=Σx·u, yp=Σx·Wout —
    // all independent -> one fused 5-step shuffle chain per row.
    {
        f32x4 u2v = *(const f32x4*)&u2s[l32*4];
        f32x4 wov = *(const f32x4*)&wos[l32*4];
        float S1v = scs[0], S0v = scs[1];
#pragma unroll
        for (int rr = wv*2 + half; rr < 32; rr += 8) {
            f16x4 xv = *(const f16x4*)&out0_s[rr][l32*4];
            float x0 = (float)xv[0], x1 = (float)xv[1], x2 = (float)xv[2], x3 = (float)xv[3];
            float s  = (x0 + x1) + (x2 + x3);
            float q  = (x0*x0 + x1*x1) + (x2*x2 + x3*x3);
            float d  = (x0*u2v[0] + x1*u2v[1]) + (x2*u2v[2] + x3*u2v[3]);
            float yp = (x0*wov[0] + x1*wov[1]) + (x2*wov[2] + x3*wov[3]);
#pragma unroll
            for (int off = 16; off > 0; off >>= 1) {
                s  += __shfl_xor(s,  off, 64);
                q  += __shfl_xor(q,  off, 64);
                d  += __shfl_xor(d,  off, 64);
                yp += __shfl_xor(yp, off, 64);
            }
            if (l32 == 0 && rr >= 1 && rr <= 30) {
                float mu  = s * (1.f/128.f);
                float inv = rsqrtf(q*(1.f/128.f) - mu*mu + LN_EPS);
                ss[rr]  = inv*(d - mu*S1v) + S0v;   // == LN2(out1[rr]) . v2
                yrs[rr] = yp;                        // == out1[rr] . Wout
            }
        }
    }
    __syncthreads();

    if (tid < C3) {
        int n = n0 + tid;
        if (n < NN) {
            int r = tid + 2;
            y[(size_t)b*NN + n] = yrs[r] + bout[0] + cls[r]*ss[r-1] + chs[r]*ss[r+1];
        }
    }
}

// ---------------- launcher ----------------
extern "C" void kernel_launch(void* const* d_in, const int* in_sizes, int n_in,
                              void* d_out, int out_size, void* d_ws, size_t ws_size,
                              hipStream_t stream)
{
    (void)in_sizes; (void)n_in; (void)out_size; (void)ws_size;
    const float* x    = (const float*)d_in[0];
    const float* A_hat= (const float*)d_in[1];
    const float* W1   = (const float*)d_in[2];
    const float* b1   = (const float*)d_in[3];
    const float* W2   = (const float*)d_in[4];
    const float* b2   = (const float*)d_in[5];
    const float* Wg1  = (const float*)d_in[6];
    const float* Wg2  = (const float*)d_in[7];
    const float* g1   = (const float*)d_in[8];
    const float* lb1  = (const float*)d_in[9];
    const float* g2   = (const float*)d_in[10];
    const float* lb2  = (const float*)d_in[11];
    const float* Wout = (const float*)d_in[12];
    const float* bout = (const float*)d_in[13];
    float* y = (float*)d_out;

    // ws: [0,32K) h1 f16 | [32K,64K) Wg1^T f16 | [64K,+512) u2 | [66560,+8) sc |
    //     [80K,+8K) clo | [88K,+8K) chi | [1M, 1M+32M) out0 f16
    char* ws = (char*)d_ws;
    f16*   h1h  = (f16*)(ws + 0);
    f16*   wg1T = (f16*)(ws + 32768);
    float* u2   = (float*)(ws + 65536);
    float* sc   = (float*)(ws + 66560);
    float* clo  = (float*)(ws + 81920);
    float* chi  = (float*)(ws + 90112);
    f16*   out0 = (f16*)(ws + (1u << 20));

    k_prep<<<dim3(74),                   256, 0, stream>>>(x, W1, b1, Wg1, Wg2, Wout, A_hat,
                                                           g2, lb2,
                                                           h1h, wg1T, u2, sc, clo, chi);
    k_enc <<<dim3(NG/256),               256, 0, stream>>>(W2, b2, h1h, out0);
    k_gcn <<<dim3((NN + C3 - 1)/C3, B_), 256, 0, stream>>>(clo, chi, g1, lb1,
                                                           Wout, bout, u2, sc, wg1T, out0, y);
}

// Round 3
// 440.078 us; speedup vs baseline: 1.0299x; 1.0299x over previous
//
#include <hip/hip_runtime.h>

// ChainGNN: B=64, ENC_IN=64, ENC_HID=256, N=2048, GH=128
// Exploits: (1) A_hat tridiagonal (chain) -> neighbor mix, not dense matmul
//           (2) layer-2 collapse: y = out1@Wout + A*(LN(out1)@(Wg2@Wout)) + bout
//           (3) f16 MFMA for encoder GEMM (268MB W2 read is the HBM floor) and layer-1 GEMM
// R4: k_enc 256-col blocks -> 1KB contiguous per W2 row per DMA instr.
// R5: k_gcn reduction overhaul (LN2 algebraic collapse, half-wave fused reductions).
// R6: k_enc counted-vmcnt pipeline (2 tiles in flight across barriers). NULL -> k_enc
//     is at its compulsory-read floor, not latency-starved.
// R7: k_gcn critical-path cut (A/B probe on k_gcn dominance; k_enc/k_prep untouched):
//     - out1 never materialized: neighbor mix fused into LN2 pass (registers, f32).
//       Removes one 30x128 LDS RMW pass and 2 of 6 barriers.
//     - 16-lane row groups, 8 ch/lane for LN1+LN2: butterfly 5->4 steps, passes 4->2,
//       cross-lane ops/thread 120->48 (each shuffle carries a serializing lgkm wait).

#define B_    64
#define EIN   64
#define EHID  256
#define NN    2048
#define GH    128
#define NG    (NN*GH)          // 262144
#define LN_EPS 1e-5f
#define C3    28               // nodes per k_gcn block (ext rows = 32 = 2 MFMA m-groups)

typedef _Float16 f16;
typedef _Float16 f16x8 __attribute__((ext_vector_type(8)));
typedef _Float16 f16x4 __attribute__((ext_vector_type(4)));
typedef _Float16 f16x2 __attribute__((ext_vector_type(2)));
typedef float    f32x4 __attribute__((ext_vector_type(4)));
typedef unsigned int u32;

#define AS1 __attribute__((address_space(1)))
#define AS3 __attribute__((address_space(3)))

__device__ __forceinline__ float wred64(float v) {
#pragma unroll
    for (int off = 32; off > 0; off >>= 1) v += __shfl_xor(v, off, 64);
    return v;
}

// ---- K1: h1=relu(x@W1+b1) f16 | Wg1^T f16 | u2=g2*(Wg2@Wout), S1/S0 scalars |
//          clo/chi off-diagonals ----
__global__ __launch_bounds__(256) void k_prep(
    const float* __restrict__ x,  const float* __restrict__ W1, const float* __restrict__ b1,
    const float* __restrict__ Wg1,const float* __restrict__ Wg2,const float* __restrict__ Wout,
    const float* __restrict__ A_hat,
    const float* __restrict__ ln_g2, const float* __restrict__ ln_b2,
    f16* __restrict__ h1h, f16* __restrict__ wg1T,
    float* __restrict__ u2, float* __restrict__ sc,
    float* __restrict__ clo, float* __restrict__ chi)
{
    int bid = blockIdx.x, tid = threadIdx.x;
    if (bid < 64) {
        int b = bid, j = tid;
        float acc = b1[j];
#pragma unroll 8
        for (int k = 0; k < EIN; ++k) acc = fmaf(x[b*EIN + k], W1[k*EHID + j], acc);
        h1h[b*EHID + j] = (f16)fmaxf(acc, 0.f);
    } else if (bid == 64) {
        __shared__ float tu[GH], tb[GH];
        if (tid < GH) {
            float s = 0.f;                       // v2[c] = (Wg2 @ Wout)[c]
            for (int j = 0; j < GH; ++j) s = fmaf(Wg2[tid*GH + j], Wout[j], s);
            float uu = ln_g2[tid] * s;           // u = g2 .* v2
            u2[tid] = uu;
            tu[tid] = uu;
            tb[tid] = ln_b2[tid] * s;            // b2 .* v2
        }
        __syncthreads();
        if (tid < 64) {
            float a = tu[tid] + tu[tid + 64];
            float b = tb[tid] + tb[tid + 64];
            a = wred64(a); b = wred64(b);
            if (tid == 0) { sc[0] = a; sc[1] = b; }   // S1, S0
        }
    } else if (bid == 65) {
        for (int i = tid; i < GH*GH; i += 256) {
            int n = i >> 7, k = i & 127;          // wg1T[n][k] = Wg1[k][n]
            wg1T[i] = (f16)Wg1[k*GH + n];
        }
    } else {
        int n = (bid - 66) * 256 + tid;           // bids 66..73 cover n = 0..2047
        clo[n] = (n >= 1)    ? A_hat[(size_t)n*NN + (n-1)] : 0.f;
        chi[n] = (n <= NN-2) ? A_hat[(size_t)n*NN + (n+1)] : 0.f;
    }
}

// ---- K2: out0 = h1 @ W2 + b2  (M=64,K=256,N=262144), f16 out ----
// 256 cols/block. W2 staged 32x256 fp32 double-buffered via global_load_lds dwordx4.
// R6 pipeline: per K-step: [s_waitcnt vmcnt(8); s_barrier; issue af(kk+1);
// compute(kk); s_barrier; stage(kk+2)]. vmcnt queue per wave (oldest->newest):
// stage(kk)[8], af(kk)[4], stage(kk+1)[8] -> vmcnt(8) retires exactly tile kk + af(kk).
__global__ __launch_bounds__(256) void k_enc(
    const float* __restrict__ W2, const float* __restrict__ b2,
    const f16* __restrict__ h1h, f16* __restrict__ out0)
{
    __shared__ float w2s[2][16*516];      // 2 x 33024 B

    int tid = threadIdx.x;
    int L = tid & 63, wv = tid >> 6, hi = L >> 4, lo = L & 15;
    int c0 = blockIdx.x * 256;

    auto stage = [&](int kk, int nb) {
#pragma unroll
        for (int s = 0; s < 8; ++s) {
            int r = wv*8 + s;
            const float* gp = W2 + (size_t)(kk*32 + r) * NG + c0 + L*4;
            float* ldst = &w2s[nb][(r >> 1)*516 + (r & 1)*256];
            __builtin_amdgcn_global_load_lds((const AS1 void*)gp, (AS3 void*)ldst, 16, 0, 0);
        }
    };

    f16x8 afq[2][4];                      // A-fragment double buffer (regs)
    auto load_af = [&](int kk, int pb) {
#pragma unroll
        for (int bg = 0; bg < 4; ++bg)
            afq[pb][bg] = *(const f16x8*)(h1h + ((bg*16 + lo) << 8) + kk*32 + hi*8);
    };

    // prologue: queue order = af(0)[4], stage(0)[8], stage(1)[8]
    load_af(0, 0);
    asm volatile("" ::: "memory");        // pin af(0) issue before stage(0)
    stage(0, 0);
    stage(1, 1);

    f32x4 acc[4][4];
#pragma unroll
    for (int bg = 0; bg < 4; ++bg)
#pragma unroll
        for (int t = 0; t < 4; ++t) acc[bg][t] = f32x4{0.f, 0.f, 0.f, 0.f};

#pragma unroll
    for (int kk = 0; kk < 8; ++kk) {
        // retire tile kk (my 8 stage loads) + af(kk); leave stage(kk+1) in flight
        if (kk < 7) asm volatile("s_waitcnt vmcnt(8)" ::: "memory");
        else        asm volatile("s_waitcnt vmcnt(0)" ::: "memory");
        __builtin_amdgcn_s_barrier();     // all waves' tile-kk rows resident
        asm volatile("" ::: "memory");    // no ds_read hoisted above the barrier

        if (kk < 7) load_af(kk + 1, (kk + 1) & 1);   // queue pos: before stage(kk+2)

        const float* wb = w2s[kk & 1];
        f16x8 bf[4];
#pragma unroll
        for (int t = 0; t < 4; ++t)
#pragma unroll
            for (int j = 0; j < 8; ++j) {
                int row = hi*8 + j;
                bf[t][j] = (f16)wb[(row >> 1)*516 + (row & 1)*256 + wv*64 + t*16 + lo];
            }

#pragma unroll
        for (int bg = 0; bg < 4; ++bg)
#pragma unroll
            for (int t = 0; t < 4; ++t)
                acc[bg][t] = __builtin_amdgcn_mfma_f32_16x16x32_f16(afq[kk & 1][bg], bf[t], acc[bg][t], 0, 0, 0);

        asm volatile("" ::: "memory");    // all buf[kk&1] reads retired (fed MFMAs)
        __builtin_amdgcn_s_barrier();     // all waves done reading buf[kk&1]
        asm volatile("" ::: "memory");    // stage not hoisted above barrier
        if (kk < 6) stage(kk + 2, kk & 1);
    }

    float bv[4];
#pragma unroll
    for (int t = 0; t < 4; ++t) bv[t] = b2[c0 + wv*64 + t*16 + lo];
#pragma unroll
    for (int bg = 0; bg < 4; ++bg)
#pragma unroll
        for (int t = 0; t < 4; ++t)
#pragma unroll
            for (int r = 0; r < 4; ++r) {
                int brow = bg*16 + hi*4 + r;      // C/D: row=(lane>>4)*4+reg, col=lane&15
                out0[(size_t)brow * NG + c0 + wv*64 + t*16 + lo] = (f16)(acc[bg][t][r] + bv[t]);
            }
}

// ---- K3 (fused GCN1+GCN2) R7: per (b, 28-node chunk) ->
//   LN1 (16-lane groups) -> Wx0 = h0@Wg1 (MFMA) -> fused mix+LN2 reduction
//   (out1 computed in registers, never materialized) -> y.
__global__ __launch_bounds__(256) void k_gcn(
    const float* __restrict__ clo, const float* __restrict__ chi,
    const float* __restrict__ ln_g1, const float* __restrict__ ln_b1,
    const float* __restrict__ Wout, const float* __restrict__ bout,
    const float* __restrict__ u2, const float* __restrict__ sc,
    const f16* __restrict__ wg1T,
    const f16* __restrict__ out0, float* __restrict__ y)
{
    __shared__ f16 out0_s[32][136];      // ext rows: nodes n0-2 .. n0+29 (stays pristine)
    __shared__ f16 h0s[32][136];
    __shared__ f16 wx0_s[32][136];
    __shared__ alignas(16) float g1s[GH], b1s[GH], u2s[GH], wos[GH];
    __shared__ float cls[32], chs[32];
    __shared__ float ss[32], yrs[32], scs[2];

    int tid = threadIdx.x;
    int n0 = blockIdx.x * C3;
    int b  = blockIdx.y;

    for (int i = tid; i < 32*16; i += 256) {
        int r = i >> 4, gv = i & 15;
        int n = n0 - 2 + r;
        f16x8 v = {0,0,0,0,0,0,0,0};
        if (n >= 0 && n < NN) v = *(const f16x8*)(out0 + ((size_t)b*NN + n)*GH + gv*8);
        *(f16x8*)&out0_s[r][gv*8] = v;
    }
    if (tid < GH) {
        g1s[tid] = ln_g1[tid]; b1s[tid] = ln_b1[tid];
        u2s[tid] = u2[tid];    wos[tid] = Wout[tid];
    } else if (tid < GH + 32) {
        int r = tid - GH, n = n0 - 2 + r;
        bool ok = (n >= 0 && n < NN);
        cls[r] = ok ? clo[n] : 0.f;
        chs[r] = ok ? chi[n] : 0.f;
    } else if (tid == GH + 32) {
        scs[0] = sc[0]; scs[1] = sc[1];
    }
    __syncthreads();

    int L = tid & 63, wv = tid >> 6, hi = L >> 4, lo = L & 15;

    // LN1: one ext row per 16-lane group, 8 ch/lane, 2 passes, 4-step butterfly
    {
        f32x4 g1a = *(const f32x4*)&g1s[lo*8],     b1a = *(const f32x4*)&b1s[lo*8];
        f32x4 g1b = *(const f32x4*)&g1s[lo*8 + 4], b1b = *(const f32x4*)&b1s[lo*8 + 4];
#pragma unroll
        for (int p = 0; p < 2; ++p) {
            int r = wv*4 + hi + p*16;
            f16x8 xv = *(const f16x8*)&out0_s[r][lo*8];
            float xf[8];
#pragma unroll
            for (int c2 = 0; c2 < 8; ++c2) xf[c2] = (float)xv[c2];
            float s = 0.f, qq = 0.f;
#pragma unroll
            for (int c2 = 0; c2 < 8; ++c2) { s += xf[c2]; qq += xf[c2]*xf[c2]; }
#pragma unroll
            for (int off = 8; off > 0; off >>= 1) {
                s  += __shfl_xor(s,  off, 64);
                qq += __shfl_xor(qq, off, 64);
            }
            float mu  = s * (1.f/128.f);
            float inv = rsqrtf(qq*(1.f/128.f) - mu*mu + LN_EPS);
            f16x8 h;
            h[0] = (f16)((xf[0] - mu)*inv*g1a[0] + b1a[0]);
            h[1] = (f16)((xf[1] - mu)*inv*g1a[1] + b1a[1]);
            h[2] = (f16)((xf[2] - mu)*inv*g1a[2] + b1a[2]);
            h[3] = (f16)((xf[3] - mu)*inv*g1a[3] + b1a[3]);
            h[4] = (f16)((xf[4] - mu)*inv*g1b[0] + b1b[0]);
            h[5] = (f16)((xf[5] - mu)*inv*g1b[1] + b1b[1]);
            h[6] = (f16)((xf[6] - mu)*inv*g1b[2] + b1b[2]);
            h[7] = (f16)((xf[7] - mu)*inv*g1b[3] + b1b[3]);
            *(f16x8*)&h0s[r][lo*8] = h;
        }
    }
    __syncthreads();

    // Wx0 = h0 @ Wg1 : M=32, N=128, K=128. B fragments straight from L2-hot wg1T.
    f32x4 acc[2][2];
#pragma unroll
    for (int mg = 0; mg < 2; ++mg)
#pragma unroll
        for (int nt = 0; nt < 2; ++nt) acc[mg][nt] = f32x4{0.f, 0.f, 0.f, 0.f};

#pragma unroll
    for (int kk = 0; kk < 4; ++kk) {
        f16x8 af[2], bfr[2];
#pragma unroll
        for (int mg = 0; mg < 2; ++mg)
            af[mg] = *(const f16x8*)&h0s[mg*16 + lo][kk*32 + hi*8];
#pragma unroll
        for (int nt = 0; nt < 2; ++nt) {
            int n = wv*32 + nt*16 + lo;
            bfr[nt] = *(const f16x8*)(wg1T + n*GH + kk*32 + hi*8);
        }
#pragma unroll
        for (int mg = 0; mg < 2; ++mg)
#pragma unroll
            for (int nt = 0; nt < 2; ++nt)
                acc[mg][nt] = __builtin_amdgcn_mfma_f32_16x16x32_f16(af[mg], bfr[nt], acc[mg][nt], 0, 0, 0);
    }
#pragma unroll
    for (int mg = 0; mg < 2; ++mg)
#pragma unroll
        for (int nt = 0; nt < 2; ++nt)
#pragma unroll
            for (int r = 0; r < 4; ++r)
                wx0_s[mg*16 + hi*4 + r][wv*32 + nt*16 + lo] = (f16)acc[mg][nt][r];
    __syncthreads();

    // Fused mix + LN2-collapsed reduction: out1[r] = out0[r] + cls[r]*Wx0[r-1]
    // + chs[r]*Wx0[r+1] built in registers (f32); reduce [s,q,d,yp] in one
    // 4-step butterfly. Rows r=0,31 compute with clamped neighbors, discarded.
    {
        f32x4 u2a = *(const f32x4*)&u2s[lo*8],     woa = *(const f32x4*)&wos[lo*8];
        f32x4 u2b = *(const f32x4*)&u2s[lo*8 + 4], wob = *(const f32x4*)&wos[lo*8 + 4];
        float S1v = scs[0], S0v = scs[1];
#pragma unroll
        for (int p = 0; p < 2; ++p) {
            int r  = wv*4 + hi + p*16;
            int rm = (r >= 1)  ? r - 1 : 0;
            int rp = (r <= 30) ? r + 1 : 31;
            float c_lo = cls[r], c_hi = chs[r];
            f16x8 ov = *(const f16x8*)&out0_s[r][lo*8];
            f16x8 av = *(const f16x8*)&wx0_s[rm][lo*8];
            f16x8 cv = *(const f16x8*)&wx0_s[rp][lo*8];
            float s = 0.f, qq = 0.f, d = 0.f, yp = 0.f;
#pragma unroll
            for (int c2 = 0; c2 < 8; ++c2) {
                float xx = (float)ov[c2] + c_lo*(float)av[c2] + c_hi*(float)cv[c2];
                float uc = (c2 < 4) ? u2a[c2] : u2b[c2-4];
                float wc = (c2 < 4) ? woa[c2] : wob[c2-4];
                s += xx; qq += xx*xx; d += xx*uc; yp += xx*wc;
            }
#pragma unroll
            for (int off = 8; off > 0; off >>= 1) {
                s  += __shfl_xor(s,  off, 64);
                qq += __shfl_xor(qq, off, 64);
                d  += __shfl_xor(d,  off, 64);
                yp += __shfl_xor(yp, off, 64);
            }
            if (lo == 0 && r >= 1 && r <= 30) {
                float mu  = s * (1.f/128.f);
                float inv = rsqrtf(qq*(1.f/128.f) - mu*mu + LN_EPS);
                ss[r]  = inv*(d - mu*S1v) + S0v;   // == LN2(out1[r]) . v2
                yrs[r] = yp;                        // == out1[r] . Wout
            }
        }
    }
    __syncthreads();

    if (tid < C3) {
        int n = n0 + tid;
        if (n < NN) {
            int r = tid + 2;
            y[(size_t)b*NN + n] = yrs[r] + bout[0] + cls[r]*ss[r-1] + chs[r]*ss[r+1];
        }
    }
}

// ---------------- launcher ----------------
extern "C" void kernel_launch(void* const* d_in, const int* in_sizes, int n_in,
                              void* d_out, int out_size, void* d_ws, size_t ws_size,
                              hipStream_t stream)
{
    (void)in_sizes; (void)n_in; (void)out_size; (void)ws_size;
    const float* x    = (const float*)d_in[0];
    const float* A_hat= (const float*)d_in[1];
    const float* W1   = (const float*)d_in[2];
    const float* b1   = (const float*)d_in[3];
    const float* W2   = (const float*)d_in[4];
    const float* b2   = (const float*)d_in[5];
    const float* Wg1  = (const float*)d_in[6];
    const float* Wg2  = (const float*)d_in[7];
    const float* g1   = (const float*)d_in[8];
    const float* lb1  = (const float*)d_in[9];
    const float* g2   = (const float*)d_in[10];
    const float* lb2  = (const float*)d_in[11];
    const float* Wout = (const float*)d_in[12];
    const float* bout = (const float*)d_in[13];
    float* y = (float*)d_out;

    // ws: [0,32K) h1 f16 | [32K,64K) Wg1^T f16 | [64K,+512) u2 | [66560,+8) sc |
    //     [80K,+8K) clo | [88K,+8K) chi | [1M, 1M+32M) out0 f16
    char* ws = (char*)d_ws;
    f16*   h1h  = (f16*)(ws + 0);
    f16*   wg1T = (f16*)(ws + 32768);
    float* u2   = (float*)(ws + 65536);
    float* sc   = (float*)(ws + 66560);
    float* clo  = (float*)(ws + 81920);
    float* chi  = (float*)(ws + 90112);
    f16*   out0 = (f16*)(ws + (1u << 20));

    k_prep<<<dim3(74),                   256, 0, stream>>>(x, W1, b1, Wg1, Wg2, Wout, A_hat,
                                                           g2, lb2,
                                                           h1h, wg1T, u2, sc, clo, chi);
    k_enc <<<dim3(NG/256),               256, 0, stream>>>(W2, b2, h1h, out0);
    k_gcn <<<dim3((NN + C3 - 1)/C3, B_), 256, 0, stream>>>(clo, chi, g1, lb1,
                                                           Wout, bout, u2, sc, wg1T, out0, y);
}

// Round 5
// 435.857 us; speedup vs baseline: 1.0398x; 1.0097x over previous
//
#include <hip/hip_runtime.h>

// ChainGNN: B=64, ENC_IN=64, ENC_HID=256, N=2048, GH=128
// Exploits: (1) A_hat tridiagonal (chain) -> neighbor mix, not dense matmul
//           (2) layer-2 collapse: y = out1@Wout + A*(LN(out1)@(Wg2@Wout)) + bout
//           (3) f16 MFMA for encoder GEMM (268MB W2 read is the HBM floor) and layer-1 GEMM
// R4: k_enc 256-col blocks -> 1KB contiguous per W2 row per DMA instr.
// R5: k_gcn reduction overhaul (LN2 algebraic collapse, half-wave fused reductions).
// R6: k_enc counted-vmcnt raw-barrier pipeline. Perf NULL (452->453); later implicated
//     in post-timing output jitter (R8 ratchet failure: pre 3.4e-3, post 5.4e-3).
// R7: k_gcn: out1 never materialized (mix fused into LN2, f32 regs); 16-lane rows. -13us.
// R8: k_gcn: out0 tile in registers, h0s/wx0_s share one LDS buffer (12KB). -1.3us.
//     FAILED post-timing consistency ratchet (call-to-call jitter, not first-call math:
//     pre-timing absmax identical to R7).
// R9: determinism fix: k_enc reverted to the harness-proven __syncthreads double-buffer
//     pipeline (R4/R5 structure; R6 proved the raw-barrier variant perf-equal, so this
//     costs nothing and removes the only hand-rolled sync construct). k_gcn keeps R8
//     structure (pure __syncthreads, clean hazard separation).

#define B_    64
#define EIN   64
#define EHID  256
#define NN    2048
#define GH    128
#define NG    (NN*GH)          // 262144
#define LN_EPS 1e-5f
#define C3    28               // nodes per k_gcn block (ext rows = 32 = 2 MFMA m-groups)

typedef _Float16 f16;
typedef _Float16 f16x8 __attribute__((ext_vector_type(8)));
typedef _Float16 f16x4 __attribute__((ext_vector_type(4)));
typedef _Float16 f16x2 __attribute__((ext_vector_type(2)));
typedef float    f32x4 __attribute__((ext_vector_type(4)));
typedef unsigned int u32;

#define AS1 __attribute__((address_space(1)))
#define AS3 __attribute__((address_space(3)))

__device__ __forceinline__ float wred64(float v) {
#pragma unroll
    for (int off = 32; off > 0; off >>= 1) v += __shfl_xor(v, off, 64);
    return v;
}

// ---- K1: h1=relu(x@W1+b1) f16 | Wg1^T f16 | u2=g2*(Wg2@Wout), S1/S0 scalars |
//          clo/chi off-diagonals ----
__global__ __launch_bounds__(256) void k_prep(
    const float* __restrict__ x,  const float* __restrict__ W1, const float* __restrict__ b1,
    const float* __restrict__ Wg1,const float* __restrict__ Wg2,const float* __restrict__ Wout,
    const float* __restrict__ A_hat,
    const float* __restrict__ ln_g2, const float* __restrict__ ln_b2,
    f16* __restrict__ h1h, f16* __restrict__ wg1T,
    float* __restrict__ u2, float* __restrict__ sc,
    float* __restrict__ clo, float* __restrict__ chi)
{
    int bid = blockIdx.x, tid = threadIdx.x;
    if (bid < 64) {
        int b = bid, j = tid;
        float acc = b1[j];
#pragma unroll 8
        for (int k = 0; k < EIN; ++k) acc = fmaf(x[b*EIN + k], W1[k*EHID + j], acc);
        h1h[b*EHID + j] = (f16)fmaxf(acc, 0.f);
    } else if (bid == 64) {
        __shared__ float tu[GH], tb[GH];
        if (tid < GH) {
            float s = 0.f;                       // v2[c] = (Wg2 @ Wout)[c]
            for (int j = 0; j < GH; ++j) s = fmaf(Wg2[tid*GH + j], Wout[j], s);
            float uu = ln_g2[tid] * s;           // u = g2 .* v2
            u2[tid] = uu;
            tu[tid] = uu;
            tb[tid] = ln_b2[tid] * s;            // b2 .* v2
        }
        __syncthreads();
        if (tid < 64) {
            float a = tu[tid] + tu[tid + 64];
            float b = tb[tid] + tb[tid + 64];
            a = wred64(a); b = wred64(b);
            if (tid == 0) { sc[0] = a; sc[1] = b; }   // S1, S0
        }
    } else if (bid == 65) {
        for (int i = tid; i < GH*GH; i += 256) {
            int n = i >> 7, k = i & 127;          // wg1T[n][k] = Wg1[k][n]
            wg1T[i] = (f16)Wg1[k*GH + n];
        }
    } else {
        int n = (bid - 66) * 256 + tid;           // bids 66..73 cover n = 0..2047
        clo[n] = (n >= 1)    ? A_hat[(size_t)n*NN + (n-1)] : 0.f;
        chi[n] = (n <= NN-2) ? A_hat[(size_t)n*NN + (n+1)] : 0.f;
    }
}

// ---- K2: out0 = h1 @ W2 + b2  (M=64,K=256,N=262144), f16 out ----
// 256 cols/block. W2 staged 32x256 fp32 double-buffered via global_load_lds dwordx4:
// one wave reads one FULL row (1KB contiguous) per instr -> DRAM-page friendly.
// LDS layout: 2-row groups (2x256 floats) + 4-float pad: group stride 516 floats
// (2064B, 16B-aligned); fragment reads land 2 lanes/bank (free).
// __syncthreads per K-step (drains vmcnt): proven stable; R6's counted-vmcnt
// variant was perf-identical and is the jitter suspect -> removed.
__global__ __launch_bounds__(256) void k_enc(
    const float* __restrict__ W2, const float* __restrict__ b2,
    const f16* __restrict__ h1h, f16* __restrict__ out0)
{
    __shared__ float w2s[2][16*516];      // 2 x 33024 B

    int tid = threadIdx.x;
    int L = tid & 63, wv = tid >> 6, hi = L >> 4, lo = L & 15;
    int c0 = blockIdx.x * 256;

    auto stage = [&](int kk, int nb) {
#pragma unroll
        for (int s = 0; s < 8; ++s) {
            int r = wv*8 + s;
            const float* gp = W2 + (size_t)(kk*32 + r) * NG + c0 + L*4;
            float* ldst = &w2s[nb][(r >> 1)*516 + (r & 1)*256];
            __builtin_amdgcn_global_load_lds((const AS1 void*)gp, (AS3 void*)ldst, 16, 0, 0);
        }
    };

    stage(0, 0);

    f32x4 acc[4][4];
#pragma unroll
    for (int bg = 0; bg < 4; ++bg)
#pragma unroll
        for (int t = 0; t < 4; ++t) acc[bg][t] = f32x4{0.f, 0.f, 0.f, 0.f};

#pragma unroll
    for (int kk = 0; kk < 8; ++kk) {
        __syncthreads();                       // drains vmcnt: tile kk resident
        if (kk < 7) stage(kk + 1, (kk + 1) & 1);

        const float* wb = w2s[kk & 1];
        f16x8 bf[4];
#pragma unroll
        for (int t = 0; t < 4; ++t)
#pragma unroll
            for (int j = 0; j < 8; ++j) {
                int row = hi*8 + j;
                bf[t][j] = (f16)wb[(row >> 1)*516 + (row & 1)*256 + wv*64 + t*16 + lo];
            }

        f16x8 af[4];
#pragma unroll
        for (int bg = 0; bg < 4; ++bg)
            af[bg] = *(const f16x8*)(h1h + ((bg*16 + lo) << 8) + kk*32 + hi*8);

#pragma unroll
        for (int bg = 0; bg < 4; ++bg)
#pragma unroll
            for (int t = 0; t < 4; ++t)
                acc[bg][t] = __builtin_amdgcn_mfma_f32_16x16x32_f16(af[bg], bf[t], acc[bg][t], 0, 0, 0);
    }

    float bv[4];
#pragma unroll
    for (int t = 0; t < 4; ++t) bv[t] = b2[c0 + wv*64 + t*16 + lo];
#pragma unroll
    for (int bg = 0; bg < 4; ++bg)
#pragma unroll
        for (int t = 0; t < 4; ++t)
#pragma unroll
            for (int r = 0; r < 4; ++r) {
                int brow = bg*16 + hi*4 + r;      // C/D: row=(lane>>4)*4+reg, col=lane&15
                out0[(size_t)brow * NG + c0 + wv*64 + t*16 + lo] = (f16)(acc[bg][t][r] + bv[t]);
            }
}

// ---- K3 (fused GCN1+GCN2) R8: per (b, 28-node chunk).
// Thread owns rows r = wv*4+hi+p*16 (p=0,1), channels lo*8..lo*8+7, held in regs.
// LN1 (reg) -> hw_s -> Wx0 = h0@Wg1 (MFMA, output back into hw_s) ->
// fused mix+LN2-collapsed reduction (out1 in regs, never materialized) -> y.
__global__ __launch_bounds__(256) void k_gcn(
    const float* __restrict__ clo, const float* __restrict__ chi,
    const float* __restrict__ ln_g1, const float* __restrict__ ln_b1,
    const float* __restrict__ Wout, const float* __restrict__ bout,
    const float* __restrict__ u2, const float* __restrict__ sc,
    const f16* __restrict__ wg1T,
    const f16* __restrict__ out0, float* __restrict__ y)
{
    __shared__ f16 hw_s[32][136];        // LN1 output h0, then reused for Wx0
    __shared__ alignas(16) float g1s[GH], b1s[GH], u2s[GH], wos[GH];
    __shared__ float cls[32], chs[32];
    __shared__ float ss[32], yrs[32], scs[2];

    int tid = threadIdx.x;
    int n0 = blockIdx.x * C3;
    int b  = blockIdx.y;
    int L = tid & 63, wv = tid >> 6, hi = L >> 4, lo = L & 15;

    // out0 tile -> registers. 16 lanes (lo=0..15) x 16B = 256B contiguous per row.
    float xf[2][8];
#pragma unroll
    for (int p = 0; p < 2; ++p) {
        int r = wv*4 + hi + p*16;
        int n = n0 - 2 + r;
        f16x8 v = {0,0,0,0,0,0,0,0};
        if (n >= 0 && n < NN) v = *(const f16x8*)(out0 + ((size_t)b*NN + n)*GH + lo*8);
#pragma unroll
        for (int c2 = 0; c2 < 8; ++c2) xf[p][c2] = (float)v[c2];
    }

    if (tid < GH) {
        g1s[tid] = ln_g1[tid]; b1s[tid] = ln_b1[tid];
        u2s[tid] = u2[tid];    wos[tid] = Wout[tid];
    } else if (tid < GH + 32) {
        int r = tid - GH, n = n0 - 2 + r;
        bool ok = (n >= 0 && n < NN);
        cls[r] = ok ? clo[n] : 0.f;
        chs[r] = ok ? chi[n] : 0.f;
    } else if (tid == GH + 32) {
        scs[0] = sc[0]; scs[1] = sc[1];
    }

    // LN1 reductions in registers (no LDS dependence) — overlap param staging
    float mu[2], inv[2];
#pragma unroll
    for (int p = 0; p < 2; ++p) {
        float s = 0.f, qq = 0.f;
#pragma unroll
        for (int c2 = 0; c2 < 8; ++c2) { s += xf[p][c2]; qq += xf[p][c2]*xf[p][c2]; }
#pragma unroll
        for (int off = 8; off > 0; off >>= 1) {
            s  += __shfl_xor(s,  off, 64);
            qq += __shfl_xor(qq, off, 64);
        }
        mu[p]  = s * (1.f/128.f);
        inv[p] = rsqrtf(qq*(1.f/128.f) - mu[p]*mu[p] + LN_EPS);
    }
    __syncthreads();                      // params resident

    // normalize -> h0 into hw_s
    {
        f32x4 g1a = *(const f32x4*)&g1s[lo*8],     b1a = *(const f32x4*)&b1s[lo*8];
        f32x4 g1b = *(const f32x4*)&g1s[lo*8 + 4], b1b = *(const f32x4*)&b1s[lo*8 + 4];
#pragma unroll
        for (int p = 0; p < 2; ++p) {
            int r = wv*4 + hi + p*16;
            f16x8 h;
            h[0] = (f16)((xf[p][0] - mu[p])*inv[p]*g1a[0] + b1a[0]);
            h[1] = (f16)((xf[p][1] - mu[p])*inv[p]*g1a[1] + b1a[1]);
            h[2] = (f16)((xf[p][2] - mu[p])*inv[p]*g1a[2] + b1a[2]);
            h[3] = (f16)((xf[p][3] - mu[p])*inv[p]*g1a[3] + b1a[3]);
            h[4] = (f16)((xf[p][4] - mu[p])*inv[p]*g1b[0] + b1b[0]);
            h[5] = (f16)((xf[p][5] - mu[p])*inv[p]*g1b[1] + b1b[1]);
            h[6] = (f16)((xf[p][6] - mu[p])*inv[p]*g1b[2] + b1b[2]);
            h[7] = (f16)((xf[p][7] - mu[p])*inv[p]*g1b[3] + b1b[3]);
            *(f16x8*)&hw_s[r][lo*8] = h;
        }
    }
    __syncthreads();                      // h0 ready

    // Wx0 = h0 @ Wg1 : M=32, N=128, K=128. B fragments straight from L2-hot wg1T.
    f32x4 acc[2][2];
#pragma unroll
    for (int mg = 0; mg < 2; ++mg)
#pragma unroll
        for (int nt = 0; nt < 2; ++nt) acc[mg][nt] = f32x4{0.f, 0.f, 0.f, 0.f};

#pragma unroll
    for (int kk = 0; kk < 4; ++kk) {
        f16x8 af[2], bfr[2];
#pragma unroll
        for (int mg = 0; mg < 2; ++mg)
            af[mg] = *(const f16x8*)&hw_s[mg*16 + lo][kk*32 + hi*8];
#pragma unroll
        for (int nt = 0; nt < 2; ++nt) {
            int n = wv*32 + nt*16 + lo;
            bfr[nt] = *(const f16x8*)(wg1T + n*GH + kk*32 + hi*8);
        }
#pragma unroll
        for (int mg = 0; mg < 2; ++mg)
#pragma unroll
            for (int nt = 0; nt < 2; ++nt)
                acc[mg][nt] = __builtin_amdgcn_mfma_f32_16x16x32_f16(af[mg], bfr[nt], acc[mg][nt], 0, 0, 0);
    }
    __syncthreads();                      // all h0 reads retired
#pragma unroll
    for (int mg = 0; mg < 2; ++mg)
#pragma unroll
        for (int nt = 0; nt < 2; ++nt)
#pragma unroll
            for (int r = 0; r < 4; ++r)
                hw_s[mg*16 + hi*4 + r][wv*32 + nt*16 + lo] = (f16)acc[mg][nt][r];
    __syncthreads();                      // Wx0 ready

    // Fused mix + LN2-collapsed reduction: out1[r] = xf + cls*Wx0[r-1] + chs*Wx0[r+1]
    // in f32 regs; reduce [s,q,d,yp] in one 4-step butterfly.
    {
        f32x4 u2a = *(const f32x4*)&u2s[lo*8],     woa = *(const f32x4*)&wos[lo*8];
        f32x4 u2b = *(const f32x4*)&u2s[lo*8 + 4], wob = *(const f32x4*)&wos[lo*8 + 4];
        float S1v = scs[0], S0v = scs[1];
#pragma unroll
        for (int p = 0; p < 2; ++p) {
            int r  = wv*4 + hi + p*16;
            int rm = (r >= 1)  ? r - 1 : 0;
            int rp = (r <= 30) ? r + 1 : 31;
            float c_lo = cls[r], c_hi = chs[r];
            f16x8 av = *(const f16x8*)&hw_s[rm][lo*8];
            f16x8 cv = *(const f16x8*)&hw_s[rp][lo*8];
            float s = 0.f, qq = 0.f, d = 0.f, yp = 0.f;
#pragma unroll
            for (int c2 = 0; c2 < 8; ++c2) {
                float xx = xf[p][c2] + c_lo*(float)av[c2] + c_hi*(float)cv[c2];
                float uc = (c2 < 4) ? u2a[c2] : u2b[c2-4];
                float wc = (c2 < 4) ? woa[c2] : wob[c2-4];
                s += xx; qq += xx*xx; d += xx*uc; yp += xx*wc;
            }
#pragma unroll
            for (int off = 8; off > 0; off >>= 1) {
                s  += __shfl_xor(s,  off, 64);
                qq += __shfl_xor(qq, off, 64);
                d  += __shfl_xor(d,  off, 64);
                yp += __shfl_xor(yp, off, 64);
            }
            if (lo == 0 && r >= 1 && r <= 30) {
                float muv  = s * (1.f/128.f);
                float invv = rsqrtf(qq*(1.f/128.f) - muv*muv + LN_EPS);
                ss[r]  = invv*(d - muv*S1v) + S0v;   // == LN2(out1[r]) . v2
                yrs[r] = yp;                          // == out1[r] . Wout
            }
        }
    }
    __syncthreads();

    if (tid < C3) {
        int n = n0 + tid;
        if (n < NN) {
            int r = tid + 2;
            y[(size_t)b*NN + n] = yrs[r] + bout[0] + cls[r]*ss[r-1] + chs[r]*ss[r+1];
        }
    }
}

// ---------------- launcher ----------------
extern "C" void kernel_launch(void* const* d_in, const int* in_sizes, int n_in,
                              void* d_out, int out_size, void* d_ws, size_t ws_size,
                              hipStream_t stream)
{
    (void)in_sizes; (void)n_in; (void)out_size; (void)ws_size;
    const float* x    = (const float*)d_in[0];
    const float* A_hat= (const float*)d_in[1];
    const float* W1   = (const float*)d_in[2];
    const float* b1   = (const float*)d_in[3];
    const float* W2   = (const float*)d_in[4];
    const float* b2   = (const float*)d_in[5];
    const float* Wg1  = (const float*)d_in[6];
    const float* Wg2  = (const float*)d_in[7];
    const float* g1   = (const float*)d_in[8];
    const float* lb1  = (const float*)d_in[9];
    const float* g2   = (const float*)d_in[10];
    const float* lb2  = (const float*)d_in[11];
    const float* Wout = (const float*)d_in[12];
    const float* bout = (const float*)d_in[13];
    float* y = (float*)d_out;

    // ws: [0,32K) h1 f16 | [32K,64K) Wg1^T f16 | [64K,+512) u2 | [66560,+8) sc |
    //     [80K,+8K) clo | [88K,+8K) chi | [1M, 1M+32M) out0 f16
    char* ws = (char*)d_ws;
    f16*   h1h  = (f16*)(ws + 0);
    f16*   wg1T = (f16*)(ws + 32768);
    float* u2   = (float*)(ws + 65536);
    float* sc   = (float*)(ws + 66560);
    float* clo  = (float*)(ws + 81920);
    float* chi  = (float*)(ws + 90112);
    f16*   out0 = (f16*)(ws + (1u << 20));

    k_prep<<<dim3(74),                   256, 0, stream>>>(x, W1, b1, Wg1, Wg2, Wout, A_hat,
                                                           g2, lb2,
                                                           h1h, wg1T, u2, sc, clo, chi);
    k_enc <<<dim3(NG/256),               256, 0, stream>>>(W2, b2, h1h, out0);
    k_gcn <<<dim3((NN + C3 - 1)/C3, B_), 256, 0, stream>>>(clo, chi, g1, lb1,
                                                           Wout, bout, u2, sc, wg1T, out0, y);
}

// Round 6
// 432.948 us; speedup vs baseline: 1.0468x; 1.0067x over previous
//
#include <hip/hip_runtime.h>

// ChainGNN: B=64, ENC_IN=64, ENC_HID=256, N=2048, GH=128
// Exploits: (1) A_hat tridiagonal (chain) -> neighbor mix, not dense matmul
//           (2) layer-2 collapse: y = out1@Wout + A*(LN(out1)@(Wg2@Wout)) + bout
//           (3) f16 MFMA for encoder GEMM (268MB W2 read is the HBM floor) and layer-1 GEMM
// R4: k_enc 256-col blocks -> 1KB contiguous per W2 row per DMA instr.
// R5: k_gcn reduction overhaul (LN2 algebraic collapse, half-wave fused reductions).
// R6: k_enc counted-vmcnt raw-barrier pipeline. Perf NULL; implicated in post-timing
//     jitter (R8 ratchet failure) -> reverted in R9. k_enc is at its compulsory floor.
// R7: k_gcn: out1 never materialized (mix fused into LN2, f32 regs); 16-lane rows. -13us.
// R8: k_gcn: out0 tile in registers; h0s/wx0_s share one LDS buffer.
// R9: k_enc reverted to proven __syncthreads pipeline (determinism). 435.9us, stable.
// R10: k_gcn chunk x2: C3 28->60 (ext rows 32->64, 4 MFMA m-groups, p=0..3/thread).
//      Halves block count (4736->2240): wg1T L2 re-reads 155->74MB, param staging and
//      per-block barrier/fixed costs halved. Same structure/math as R8, only scaled.
//      __launch_bounds__(256,3) keeps >=3 blocks/CU.

#define B_    64
#define EIN   64
#define EHID  256
#define NN    2048
#define GH    128
#define NG    (NN*GH)          // 262144
#define LN_EPS 1e-5f
#define C3    60               // nodes per k_gcn block
#define EXT   64               // ext rows = C3+4 = 4 MFMA m-groups

typedef _Float16 f16;
typedef _Float16 f16x8 __attribute__((ext_vector_type(8)));
typedef _Float16 f16x4 __attribute__((ext_vector_type(4)));
typedef _Float16 f16x2 __attribute__((ext_vector_type(2)));
typedef float    f32x4 __attribute__((ext_vector_type(4)));
typedef unsigned int u32;

#define AS1 __attribute__((address_space(1)))
#define AS3 __attribute__((address_space(3)))

__device__ __forceinline__ float wred64(float v) {
#pragma unroll
    for (int off = 32; off > 0; off >>= 1) v += __shfl_xor(v, off, 64);
    return v;
}

// ---- K1: h1=relu(x@W1+b1) f16 | Wg1^T f16 | u2=g2*(Wg2@Wout), S1/S0 scalars |
//          clo/chi off-diagonals ----
__global__ __launch_bounds__(256) void k_prep(
    const float* __restrict__ x,  const float* __restrict__ W1, const float* __restrict__ b1,
    const float* __restrict__ Wg1,const float* __restrict__ Wg2,const float* __restrict__ Wout,
    const float* __restrict__ A_hat,
    const float* __restrict__ ln_g2, const float* __restrict__ ln_b2,
    f16* __restrict__ h1h, f16* __restrict__ wg1T,
    float* __restrict__ u2, float* __restrict__ sc,
    float* __restrict__ clo, float* __restrict__ chi)
{
    int bid = blockIdx.x, tid = threadIdx.x;
    if (bid < 64) {
        int b = bid, j = tid;
        float acc = b1[j];
#pragma unroll 8
        for (int k = 0; k < EIN; ++k) acc = fmaf(x[b*EIN + k], W1[k*EHID + j], acc);
        h1h[b*EHID + j] = (f16)fmaxf(acc, 0.f);
    } else if (bid == 64) {
        __shared__ float tu[GH], tb[GH];
        if (tid < GH) {
            float s = 0.f;                       // v2[c] = (Wg2 @ Wout)[c]
            for (int j = 0; j < GH; ++j) s = fmaf(Wg2[tid*GH + j], Wout[j], s);
            float uu = ln_g2[tid] * s;           // u = g2 .* v2
            u2[tid] = uu;
            tu[tid] = uu;
            tb[tid] = ln_b2[tid] * s;            // b2 .* v2
        }
        __syncthreads();
        if (tid < 64) {
            float a = tu[tid] + tu[tid + 64];
            float b = tb[tid] + tb[tid + 64];
            a = wred64(a); b = wred64(b);
            if (tid == 0) { sc[0] = a; sc[1] = b; }   // S1, S0
        }
    } else if (bid == 65) {
        for (int i = tid; i < GH*GH; i += 256) {
            int n = i >> 7, k = i & 127;          // wg1T[n][k] = Wg1[k][n]
            wg1T[i] = (f16)Wg1[k*GH + n];
        }
    } else {
        int n = (bid - 66) * 256 + tid;           // bids 66..73 cover n = 0..2047
        clo[n] = (n >= 1)    ? A_hat[(size_t)n*NN + (n-1)] : 0.f;
        chi[n] = (n <= NN-2) ? A_hat[(size_t)n*NN + (n+1)] : 0.f;
    }
}

// ---- K2: out0 = h1 @ W2 + b2  (M=64,K=256,N=262144), f16 out ----
// 256 cols/block. W2 staged 32x256 fp32 double-buffered via global_load_lds dwordx4:
// one wave reads one FULL row (1KB contiguous) per instr -> DRAM-page friendly.
// LDS layout: 2-row groups (2x256 floats) + 4-float pad: group stride 516 floats
// (2064B, 16B-aligned); fragment reads land 2 lanes/bank (free).
// __syncthreads per K-step (drains vmcnt): proven stable; R6's counted-vmcnt
// variant was perf-identical and is the jitter suspect -> removed.
__global__ __launch_bounds__(256) void k_enc(
    const float* __restrict__ W2, const float* __restrict__ b2,
    const f16* __restrict__ h1h, f16* __restrict__ out0)
{
    __shared__ float w2s[2][16*516];      // 2 x 33024 B

    int tid = threadIdx.x;
    int L = tid & 63, wv = tid >> 6, hi = L >> 4, lo = L & 15;
    int c0 = blockIdx.x * 256;

    auto stage = [&](int kk, int nb) {
#pragma unroll
        for (int s = 0; s < 8; ++s) {
            int r = wv*8 + s;
            const float* gp = W2 + (size_t)(kk*32 + r) * NG + c0 + L*4;
            float* ldst = &w2s[nb][(r >> 1)*516 + (r & 1)*256];
            __builtin_amdgcn_global_load_lds((const AS1 void*)gp, (AS3 void*)ldst, 16, 0, 0);
        }
    };

    stage(0, 0);

    f32x4 acc[4][4];
#pragma unroll
    for (int bg = 0; bg < 4; ++bg)
#pragma unroll
        for (int t = 0; t < 4; ++t) acc[bg][t] = f32x4{0.f, 0.f, 0.f, 0.f};

#pragma unroll
    for (int kk = 0; kk < 8; ++kk) {
        __syncthreads();                       // drains vmcnt: tile kk resident
        if (kk < 7) stage(kk + 1, (kk + 1) & 1);

        const float* wb = w2s[kk & 1];
        f16x8 bf[4];
#pragma unroll
        for (int t = 0; t < 4; ++t)
#pragma unroll
            for (int j = 0; j < 8; ++j) {
                int row = hi*8 + j;
                bf[t][j] = (f16)wb[(row >> 1)*516 + (row & 1)*256 + wv*64 + t*16 + lo];
            }

        f16x8 af[4];
#pragma unroll
        for (int bg = 0; bg < 4; ++bg)
            af[bg] = *(const f16x8*)(h1h + ((bg*16 + lo) << 8) + kk*32 + hi*8);

#pragma unroll
        for (int bg = 0; bg < 4; ++bg)
#pragma unroll
            for (int t = 0; t < 4; ++t)
                acc[bg][t] = __builtin_amdgcn_mfma_f32_16x16x32_f16(af[bg], bf[t], acc[bg][t], 0, 0, 0);
    }

    float bv[4];
#pragma unroll
    for (int t = 0; t < 4; ++t) bv[t] = b2[c0 + wv*64 + t*16 + lo];
#pragma unroll
    for (int bg = 0; bg < 4; ++bg)
#pragma unroll
        for (int t = 0; t < 4; ++t)
#pragma unroll
            for (int r = 0; r < 4; ++r) {
                int brow = bg*16 + hi*4 + r;      // C/D: row=(lane>>4)*4+reg, col=lane&15
                out0[(size_t)brow * NG + c0 + wv*64 + t*16 + lo] = (f16)(acc[bg][t][r] + bv[t]);
            }
}

// ---- K3 (fused GCN1+GCN2) R10: per (b, 60-node chunk), ext rows 64.
// Thread owns rows r = wv*4+hi+p*16 (p=0..3), channels lo*8..lo*8+7, held in regs.
// LN1 (reg) -> hw_s -> Wx0 = h0@Wg1 (MFMA M=64, output back into hw_s) ->
// fused mix+LN2-collapsed reduction (out1 in regs, never materialized) -> y.
__global__ __launch_bounds__(256, 3) void k_gcn(
    const float* __restrict__ clo, const float* __restrict__ chi,
    const float* __restrict__ ln_g1, const float* __restrict__ ln_b1,
    const float* __restrict__ Wout, const float* __restrict__ bout,
    const float* __restrict__ u2, const float* __restrict__ sc,
    const f16* __restrict__ wg1T,
    const f16* __restrict__ out0, float* __restrict__ y)
{
    __shared__ f16 hw_s[EXT][136];       // LN1 output h0, then reused for Wx0
    __shared__ alignas(16) float g1s[GH], b1s[GH], u2s[GH], wos[GH];
    __shared__ float cls[EXT], chs[EXT];
    __shared__ float ss[EXT], yrs[EXT], scs[2];

    int tid = threadIdx.x;
    int n0 = blockIdx.x * C3;
    int b  = blockIdx.y;
    int L = tid & 63, wv = tid >> 6, hi = L >> 4, lo = L & 15;

    // out0 tile -> registers. 16 lanes (lo=0..15) x 16B = 256B contiguous per row.
    float xf[4][8];
#pragma unroll
    for (int p = 0; p < 4; ++p) {
        int r = wv*4 + hi + p*16;
        int n = n0 - 2 + r;
        f16x8 v = {0,0,0,0,0,0,0,0};
        if (n >= 0 && n < NN) v = *(const f16x8*)(out0 + ((size_t)b*NN + n)*GH + lo*8);
#pragma unroll
        for (int c2 = 0; c2 < 8; ++c2) xf[p][c2] = (float)v[c2];
    }

    if (tid < GH) {
        g1s[tid] = ln_g1[tid]; b1s[tid] = ln_b1[tid];
        u2s[tid] = u2[tid];    wos[tid] = Wout[tid];
    } else if (tid < GH + EXT) {
        int r = tid - GH, n = n0 - 2 + r;
        bool ok = (n >= 0 && n < NN);
        cls[r] = ok ? clo[n] : 0.f;
        chs[r] = ok ? chi[n] : 0.f;
    } else if (tid == GH + EXT) {
        scs[0] = sc[0]; scs[1] = sc[1];
    }

    // LN1 reductions in registers (no LDS dependence) — overlap param staging
    float mu[4], inv[4];
#pragma unroll
    for (int p = 0; p < 4; ++p) {
        float s = 0.f, qq = 0.f;
#pragma unroll
        for (int c2 = 0; c2 < 8; ++c2) { s += xf[p][c2]; qq += xf[p][c2]*xf[p][c2]; }
#pragma unroll
        for (int off = 8; off > 0; off >>= 1) {
            s  += __shfl_xor(s,  off, 64);
            qq += __shfl_xor(qq, off, 64);
        }
        mu[p]  = s * (1.f/128.f);
        inv[p] = rsqrtf(qq*(1.f/128.f) - mu[p]*mu[p] + LN_EPS);
    }
    __syncthreads();                      // params resident

    // normalize -> h0 into hw_s
    {
        f32x4 g1a = *(const f32x4*)&g1s[lo*8],     b1a = *(const f32x4*)&b1s[lo*8];
        f32x4 g1b = *(const f32x4*)&g1s[lo*8 + 4], b1b = *(const f32x4*)&b1s[lo*8 + 4];
#pragma unroll
        for (int p = 0; p < 4; ++p) {
            int r = wv*4 + hi + p*16;
            f16x8 h;
            h[0] = (f16)((xf[p][0] - mu[p])*inv[p]*g1a[0] + b1a[0]);
            h[1] = (f16)((xf[p][1] - mu[p])*inv[p]*g1a[1] + b1a[1]);
            h[2] = (f16)((xf[p][2] - mu[p])*inv[p]*g1a[2] + b1a[2]);
            h[3] = (f16)((xf[p][3] - mu[p])*inv[p]*g1a[3] + b1a[3]);
            h[4] = (f16)((xf[p][4] - mu[p])*inv[p]*g1b[0] + b1b[0]);
            h[5] = (f16)((xf[p][5] - mu[p])*inv[p]*g1b[1] + b1b[1]);
            h[6] = (f16)((xf[p][6] - mu[p])*inv[p]*g1b[2] + b1b[2]);
            h[7] = (f16)((xf[p][7] - mu[p])*inv[p]*g1b[3] + b1b[3]);
            *(f16x8*)&hw_s[r][lo*8] = h;
        }
    }
    __syncthreads();                      // h0 ready

    // Wx0 = h0 @ Wg1 : M=64, N=128, K=128. B fragments straight from L2-hot wg1T.
    f32x4 acc[4][2];
#pragma unroll
    for (int mg = 0; mg < 4; ++mg)
#pragma unroll
        for (int nt = 0; nt < 2; ++nt) acc[mg][nt] = f32x4{0.f, 0.f, 0.f, 0.f};

#pragma unroll
    for (int kk = 0; kk < 4; ++kk) {
        f16x8 af[4], bfr[2];
#pragma unroll
        for (int mg = 0; mg < 4; ++mg)
            af[mg] = *(const f16x8*)&hw_s[mg*16 + lo][kk*32 + hi*8];
#pragma unroll
        for (int nt = 0; nt < 2; ++nt) {
            int n = wv*32 + nt*16 + lo;
            bfr[nt] = *(const f16x8*)(wg1T + n*GH + kk*32 + hi*8);
        }
#pragma unroll
        for (int mg = 0; mg < 4; ++mg)
#pragma unroll
            for (int nt = 0; nt < 2; ++nt)
                acc[mg][nt] = __builtin_amdgcn_mfma_f32_16x16x32_f16(af[mg], bfr[nt], acc[mg][nt], 0, 0, 0);
    }
    __syncthreads();                      // all h0 reads retired
#pragma unroll
    for (int mg = 0; mg < 4; ++mg)
#pragma unroll
        for (int nt = 0; nt < 2; ++nt)
#pragma unroll
            for (int r = 0; r < 4; ++r)
                hw_s[mg*16 + hi*4 + r][wv*32 + nt*16 + lo] = (f16)acc[mg][nt][r];
    __syncthreads();                      // Wx0 ready

    // Fused mix + LN2-collapsed reduction: out1[r] = xf + cls*Wx0[r-1] + chs*Wx0[r+1]
    // in f32 regs; reduce [s,q,d,yp] in one 4-step butterfly.
    {
        f32x4 u2a = *(const f32x4*)&u2s[lo*8],     woa = *(const f32x4*)&wos[lo*8];
        f32x4 u2b = *(const f32x4*)&u2s[lo*8 + 4], wob = *(const f32x4*)&wos[lo*8 + 4];
        float S1v = scs[0], S0v = scs[1];
#pragma unroll
        for (int p = 0; p < 4; ++p) {
            int r  = wv*4 + hi + p*16;
            int rm = (r >= 1)       ? r - 1 : 0;
            int rp = (r <= EXT - 2) ? r + 1 : EXT - 1;
            float c_lo = cls[r], c_hi = chs[r];
            f16x8 av = *(const f16x8*)&hw_s[rm][lo*8];
            f16x8 cv = *(const f16x8*)&hw_s[rp][lo*8];
            float s = 0.f, qq = 0.f, d = 0.f, yp = 0.f;
#pragma unroll
            for (int c2 = 0; c2 < 8; ++c2) {
                float xx = xf[p][c2] + c_lo*(float)av[c2] + c_hi*(float)cv[c2];
                float uc = (c2 < 4) ? u2a[c2] : u2b[c2-4];
                float wc = (c2 < 4) ? woa[c2] : wob[c2-4];
                s += xx; qq += xx*xx; d += xx*uc; yp += xx*wc;
            }
#pragma unroll
            for (int off = 8; off > 0; off >>= 1) {
                s  += __shfl_xor(s,  off, 64);
                qq += __shfl_xor(qq, off, 64);
                d  += __shfl_xor(d,  off, 64);
                yp += __shfl_xor(yp, off, 64);
            }
            if (lo == 0 && r >= 1 && r <= EXT - 2) {
                float muv  = s * (1.f/128.f);
                float invv = rsqrtf(qq*(1.f/128.f) - muv*muv + LN_EPS);
                ss[r]  = invv*(d - muv*S1v) + S0v;   // == LN2(out1[r]) . v2
                yrs[r] = yp;                          // == out1[r] . Wout
            }
        }
    }
    __syncthreads();

    if (tid < C3) {
        int n = n0 + tid;
        if (n < NN) {
            int r = tid + 2;
            y[(size_t)b*NN + n] = yrs[r] + bout[0] + cls[r]*ss[r-1] + chs[r]*ss[r+1];
        }
    }
}

// ---------------- launcher ----------------
extern "C" void kernel_launch(void* const* d_in, const int* in_sizes, int n_in,
                              void* d_out, int out_size, void* d_ws, size_t ws_size,
                              hipStream_t stream)
{
    (void)in_sizes; (void)n_in; (void)out_size; (void)ws_size;
    const float* x    = (const float*)d_in[0];
    const float* A_hat= (const float*)d_in[1];
    const float* W1   = (const float*)d_in[2];
    const float* b1   = (const float*)d_in[3];
    const float* W2   = (const float*)d_in[4];
    const float* b2   = (const float*)d_in[5];
    const float* Wg1  = (const float*)d_in[6];
    const float* Wg2  = (const float*)d_in[7];
    const float* g1   = (const float*)d_in[8];
    const float* lb1  = (const float*)d_in[9];
    const float* g2   = (const float*)d_in[10];
    const float* lb2  = (const float*)d_in[11];
    const float* Wout = (const float*)d_in[12];
    const float* bout = (const float*)d_in[13];
    float* y = (float*)d_out;

    // ws: [0,32K) h1 f16 | [32K,64K) Wg1^T f16 | [64K,+512) u2 | [66560,+8) sc |
    //     [80K,+8K) clo | [88K,+8K) chi | [1M, 1M+32M) out0 f16
    char* ws = (char*)d_ws;
    f16*   h1h  = (f16*)(ws + 0);
    f16*   wg1T = (f16*)(ws + 32768);
    float* u2   = (float*)(ws + 65536);
    float* sc   = (float*)(ws + 66560);
    float* clo  = (float*)(ws + 81920);
    float* chi  = (float*)(ws + 90112);
    f16*   out0 = (f16*)(ws + (1u << 20));

    k_prep<<<dim3(74),                   256, 0, stream>>>(x, W1, b1, Wg1, Wg2, Wout, A_hat,
                                                           g2, lb2,
                                                           h1h, wg1T, u2, sc, clo, chi);
    k_enc <<<dim3(NG/256),               256, 0, stream>>>(W2, b2, h1h, out0);
    k_gcn <<<dim3((NN + C3 - 1)/C3, B_), 256, 0, stream>>>(clo, chi, g1, lb1,
                                                           Wout, bout, u2, sc, wg1T, out0, y);
}